// Round 14
// baseline (476.662 us; speedup 1.0000x reference)
//
#include <hip/hip_runtime.h>

// Problem constants
constexpr int B_ = 32, S_ = 512, D_ = 1024, H_ = 16, DH_ = 64, HD_ = 1024;
constexpr int M_ = B_ * S_;                 // 16384
constexpr float EPS_ = 1e-7f;
constexpr float INV_TEMP_ = 10.0f;          // 1/0.1

typedef __attribute__((ext_vector_type(8))) short bf16x8;
typedef __attribute__((ext_vector_type(4))) short bf16x4;
typedef __attribute__((ext_vector_type(4))) float f32x4;
typedef __attribute__((ext_vector_type(8))) unsigned short us8;

__device__ __forceinline__ float sigm(float x) { return 1.0f / (1.0f + __expf(-x)); }

__device__ __forceinline__ unsigned short f2bf(float f) {
    unsigned u = __float_as_uint(f);
    unsigned r = (u + 0x7FFFu + ((u >> 16) & 1u)) >> 16;   // RNE
    return (unsigned short)r;
}

#define GLL16(gp, lp) __builtin_amdgcn_global_load_lds( \
    (const __attribute__((address_space(1))) unsigned int*)(gp), \
    (__attribute__((address_space(3))) unsigned int*)(lp), 16, 0, 0)

// LDS fragment read with XOR swizzle: element = row*64 + ((k>>3 ^ (row&7))*8)
__device__ __forceinline__ bf16x8 ldsfrag64(const unsigned short* base, int row, int k) {
    int slot = ((k >> 3) ^ (row & 7)) << 3;
    return *(const bf16x8*)(base + row * 64 + slot);
}

// ---------------------------------------------------------------------------
// Concrete-dropout + bf16 cast for q/k/v inputs (reads x once).
// ---------------------------------------------------------------------------
__global__ __launch_bounds__(256)
void cd_cast3_kernel(const float* __restrict__ x,
                     const float* __restrict__ nq, const float* __restrict__ nk,
                     const float* __restrict__ nv, const float* __restrict__ pl,
                     unsigned short* __restrict__ aq, unsigned short* __restrict__ ak,
                     unsigned short* __restrict__ av)
{
    size_t i0 = ((size_t)blockIdx.x * 256 + threadIdx.x) * 8;

    float c0[3], inv1mp[3];
#pragma unroll
    for (int j = 0; j < 3; ++j) {
        float p = sigm(pl[j]);
        c0[j] = __logf(p + EPS_) - __logf(1.0f - p + EPS_);
        inv1mp[j] = 1.0f / (1.0f - p);
    }

    float4 x0 = *(const float4*)(x + i0);
    float4 x1 = *(const float4*)(x + i0 + 4);
    float xv[8] = {x0.x, x0.y, x0.z, x0.w, x1.x, x1.y, x1.z, x1.w};

    const float* ns[3] = {nq, nk, nv};
    unsigned short* os[3] = {aq, ak, av};
#pragma unroll
    for (int j = 0; j < 3; ++j) {
        float4 u0 = *(const float4*)(ns[j] + i0);
        float4 u1 = *(const float4*)(ns[j] + i0 + 4);
        float uv[8] = {u0.x, u0.y, u0.z, u0.w, u1.x, u1.y, u1.z, u1.w};
        ushort out[8];
#pragma unroll
        for (int t = 0; t < 8; ++t) {
            float lt = (c0[j] + __logf(uv[t] + EPS_) - __logf(1.0f - uv[t] + EPS_)) * INV_TEMP_;
            float dpr = sigm(lt);
            out[t] = f2bf(xv[t] * (1.0f - dpr) * inv1mp[j]);
        }
        *(us8*)(os[j] + i0) = *(us8*)out;
    }
}

// ---------------------------------------------------------------------------
// Weight cast + transpose (all 4 weights in one launch): W[k][n] -> WT[n][k] bf16
// ---------------------------------------------------------------------------
__global__ __launch_bounds__(256)
void wcast_t4_kernel(const float* __restrict__ W0, const float* __restrict__ W1,
                     const float* __restrict__ W2, const float* __restrict__ W3,
                     unsigned short* __restrict__ T0, unsigned short* __restrict__ T1,
                     unsigned short* __restrict__ T2, unsigned short* __restrict__ T3)
{
    __shared__ unsigned short t[64][72];
    int z = blockIdx.z;
    const float* W = (z & 2) ? ((z & 1) ? W3 : W2) : ((z & 1) ? W1 : W0);
    unsigned short* WT = (z & 2) ? ((z & 1) ? T3 : T2) : ((z & 1) ? T1 : T0);
    int kb = blockIdx.y * 64;
    int nb = blockIdx.x * 64;
    int tid = threadIdx.x;
#pragma unroll
    for (int i = 0; i < 4; ++i) {
        int idx = tid + i * 256;
        int r = idx >> 4, c4 = idx & 15;
        float4 v = *(const float4*)(W + (size_t)(kb + r) * 1024 + nb + c4 * 4);
        t[c4 * 4 + 0][r] = f2bf(v.x);
        t[c4 * 4 + 1][r] = f2bf(v.y);
        t[c4 * 4 + 2][r] = f2bf(v.z);
        t[c4 * 4 + 3][r] = f2bf(v.w);
    }
    __syncthreads();
#pragma unroll
    for (int i = 0; i < 4; ++i) {
        int idx = tid + i * 256;
        int r = idx >> 4, c4 = idx & 15;
        ushort4 o;
        o.x = t[r][c4 * 4 + 0];
        o.y = t[r][c4 * 4 + 1];
        o.z = t[r][c4 * 4 + 2];
        o.w = t[r][c4 * 4 + 3];
        *(ushort4*)(WT + (size_t)(nb + r) * 1024 + kb + c4 * 4) = o;
    }
}

// ---------------------------------------------------------------------------
// QKV bf16 MFMA GEMM, BK=64: swizzled-source GLL16 staging, conflict-free
// ldsfrag64 reads, vectorized LDS-bounce epilogue.
// zo=blockIdx.y: 0->qb, 1->kb, 2->vT (transposed write, fuses vtrans).
// ---------------------------------------------------------------------------
__global__ __launch_bounds__(256, 3)
void gemm_qkv_kernel(const unsigned short* __restrict__ A,
                     const unsigned short* __restrict__ BT,
                     unsigned short* __restrict__ qkb,
                     unsigned short* __restrict__ vT)
{
    const int zo = blockIdx.y;
    A  += (size_t)zo * M_ * HD_;
    BT += (size_t)zo * (1024 * 1024);

    // staging 2 x 128x64 bf16 (32KB); epilogue bounce (17.4KB) reuses it
    __shared__ unsigned short LDSU[16384];
    unsigned short* As = LDSU;            // [128][64] swizzled
    unsigned short* Bs = LDSU + 8192;     // [128][64] swizzled

    int flat = blockIdx.x;
    int swz = (flat & 7) * 128 + (flat >> 3);
    int ntile = swz & 7, mtile = swz >> 3;
    int m0 = mtile * 128, n0 = ntile * 128;

    int tid = threadIdx.x;
    int w = tid >> 6, lane = tid & 63;
    int wm = w >> 1, wn = w & 1;

    f32x4 acc[4][4];
#pragma unroll
    for (int m = 0; m < 4; ++m)
#pragma unroll
        for (int n = 0; n < 4; ++n) acc[m][n] = (f32x4){0.f, 0.f, 0.f, 0.f};

    const int sr = lane >> 3;                 // row within 8-row chunk
    const int sc = ((lane & 7) ^ sr) * 8;     // pre-swizzled source col (elems)

    const unsigned short* Ag = A + (size_t)(m0 + w * 32 + sr) * 1024 + sc;
    const unsigned short* Bg = BT + (size_t)(n0 + w * 32 + sr) * 1024 + sc;
    unsigned short* AsW = As + (w * 32) * 64;
    unsigned short* BsW = Bs + (w * 32) * 64;

    const int arow = wm * 64 + (lane & 15);
    const int brow = wn * 64 + (lane & 15);
    const int g8 = (lane >> 4) * 8;

    for (int k0 = 0; k0 < 1024; k0 += 64) {
        __syncthreads();
#pragma unroll
        for (int c = 0; c < 4; ++c) {
            GLL16(Ag + k0 + (size_t)(c * 8) * 1024, AsW + c * 512);
            GLL16(Bg + k0 + (size_t)(c * 8) * 1024, BsW + c * 512);
        }
        __syncthreads();

#pragma unroll
        for (int kk = 0; kk < 2; ++kk) {
            bf16x8 afr[4], bfr[4];
#pragma unroll
            for (int m = 0; m < 4; ++m)
                afr[m] = ldsfrag64(As, arow + m * 16, g8 + kk * 32);
#pragma unroll
            for (int n = 0; n < 4; ++n)
                bfr[n] = ldsfrag64(Bs, brow + n * 16, g8 + kk * 32);
#pragma unroll
            for (int m = 0; m < 4; ++m)
#pragma unroll
                for (int n = 0; n < 4; ++n)
                    acc[m][n] = __builtin_amdgcn_mfma_f32_16x16x32_bf16(afr[m], bfr[n], acc[m][n], 0, 0, 0);
        }
    }

    const int cr = (lane >> 4) * 4, cc = lane & 15;
    __syncthreads();   // staging LDS free for bounce

    if (zo < 2) {
        // flat bf16 output, chunked by n-frag through LDS [128][68] (32 cols used)
        unsigned short* Cb = qkb + (size_t)zo * M_ * HD_;
        for (int n = 0; n < 4; ++n) {
#pragma unroll
            for (int m = 0; m < 4; ++m)
#pragma unroll
                for (int j = 0; j < 4; ++j)
                    LDSU[(wm * 64 + m * 16 + cr + j) * 68 + wn * 16 + cc] = f2bf(acc[m][n][j]);
            __syncthreads();
#pragma unroll
            for (int t = 0; t < 2; ++t) {
                int fl = tid + t * 256;            // 0..511
                int row = fl >> 2, p = fl & 3;     // row 0..127, p 0..3
                us8 vv = *(const us8*)&LDSU[row * 68 + p * 8];
                int colg = n0 + (p >> 1) * 64 + n * 16 + (p & 1) * 8;
                *(us8*)(Cb + (size_t)(m0 + row) * 1024 + colg) = vv;
            }
            __syncthreads();
        }
    } else {
        // V slice: write vT[b,h,d,y] directly via transposed bounce LDS [32][132]
        int b = m0 >> 9, y0 = m0 & 511, h0 = n0 >> 6;
        for (int n = 0; n < 4; ++n) {
#pragma unroll
            for (int m = 0; m < 4; ++m)
#pragma unroll
                for (int j = 0; j < 4; ++j)
                    LDSU[(wn * 16 + cc) * 132 + wm * 64 + m * 16 + cr + j] = f2bf(acc[m][n][j]);
            __syncthreads();
#pragma unroll
            for (int t = 0; t < 2; ++t) {
                int fl = tid + t * 256;            // 0..511
                int cl = fl >> 4, yp = fl & 15;    // cl 0..31, yp 0..15
                us8 vv = *(const us8*)&LDSU[cl * 132 + yp * 8];
                int h = h0 + (cl >> 4), d = n * 16 + (cl & 15);
                *(us8*)(vT + ((size_t)((b * 16 + h) * 64 + d)) * 512 + y0 + yp * 8) = vv;
            }
            __syncthreads();
        }
    }
}

// ---------------------------------------------------------------------------
// O-projection GEMM, BK=64 (same staging/read pattern), RELU, fp32 out.
// ---------------------------------------------------------------------------
__global__ __launch_bounds__(256, 3)
void gemm_o_kernel(const unsigned short* __restrict__ A,
                   const unsigned short* __restrict__ BT,
                   float* __restrict__ C)
{
    __shared__ unsigned short As[128 * 64];
    __shared__ unsigned short Bs[128 * 64];

    int flat = blockIdx.x;
    int swz = (flat & 7) * 128 + (flat >> 3);
    int ntile = swz & 7, mtile = swz >> 3;
    int m0 = mtile * 128, n0 = ntile * 128;

    int tid = threadIdx.x;
    int w = tid >> 6, lane = tid & 63;
    int wm = w >> 1, wn = w & 1;

    f32x4 acc[4][4];
#pragma unroll
    for (int m = 0; m < 4; ++m)
#pragma unroll
        for (int n = 0; n < 4; ++n) acc[m][n] = (f32x4){0.f, 0.f, 0.f, 0.f};

    const int sr = lane >> 3;
    const int sc = ((lane & 7) ^ sr) * 8;

    const unsigned short* Ag = A + (size_t)(m0 + w * 32 + sr) * 1024 + sc;
    const unsigned short* Bg = BT + (size_t)(n0 + w * 32 + sr) * 1024 + sc;
    unsigned short* AsW = As + (w * 32) * 64;
    unsigned short* BsW = Bs + (w * 32) * 64;

    const int arow = wm * 64 + (lane & 15);
    const int brow = wn * 64 + (lane & 15);
    const int g8 = (lane >> 4) * 8;

    for (int k0 = 0; k0 < 1024; k0 += 64) {
        __syncthreads();
#pragma unroll
        for (int c = 0; c < 4; ++c) {
            GLL16(Ag + k0 + (size_t)(c * 8) * 1024, AsW + c * 512);
            GLL16(Bg + k0 + (size_t)(c * 8) * 1024, BsW + c * 512);
        }
        __syncthreads();

#pragma unroll
        for (int kk = 0; kk < 2; ++kk) {
            bf16x8 afr[4], bfr[4];
#pragma unroll
            for (int m = 0; m < 4; ++m)
                afr[m] = ldsfrag64(As, arow + m * 16, g8 + kk * 32);
#pragma unroll
            for (int n = 0; n < 4; ++n)
                bfr[n] = ldsfrag64(Bs, brow + n * 16, g8 + kk * 32);
#pragma unroll
            for (int m = 0; m < 4; ++m)
#pragma unroll
                for (int n = 0; n < 4; ++n)
                    acc[m][n] = __builtin_amdgcn_mfma_f32_16x16x32_bf16(afr[m], bfr[n], acc[m][n], 0, 0, 0);
        }
    }

    int cr = (lane >> 4) * 4, cc = lane & 15;
#pragma unroll
    for (int m = 0; m < 4; ++m)
#pragma unroll
        for (int n = 0; n < 4; ++n)
#pragma unroll
            for (int j = 0; j < 4; ++j) {
                int row = m0 + wm * 64 + m * 16 + cr + j;
                int col = n0 + wn * 64 + n * 16 + cc;
                C[(size_t)row * 1024 + col] = fmaxf(acc[m][n][j], 0.f);
            }
}

// ---------------------------------------------------------------------------
// Fused attention v2 (R13 champion, single change: alpha stores are REGULAR
// f32x4 stores, not non-temporal — lets L2/L3 absorb the 537MB write stream
// and cheapens the per-pass vmcnt drain at __syncthreads).
// ---------------------------------------------------------------------------
__global__ __launch_bounds__(512, 2)
void fused_attn2_kernel(const unsigned short* __restrict__ qb,
                        const unsigned short* __restrict__ kb,
                        const unsigned short* __restrict__ vT,
                        const float* __restrict__ no,
                        const float* __restrict__ pl,
                        const int* __restrict__ lengths,
                        float* __restrict__ alpha,
                        unsigned short* __restrict__ Ao)
{
    const int bh = blockIdx.x;
    const int b = bh >> 4, h = bh & 15;
    const int tid = threadIdx.x;
    const int w = tid >> 6, lane = tid & 63;
    const int g = lane >> 4, li = lane & 15;
    const int len = lengths[b];

    __shared__ unsigned short Kall[512 * 64];      // [y][64k] swizzled (8 tiles)
    __shared__ unsigned short Vall[8 * 64 * 64];   // tile yt: [d][64y] swizzled
    __shared__ unsigned short Olb[128 * 72];       // O pass tile, bf16

    const int sr = lane >> 3;
    const int sc = ((lane & 7) ^ sr) * 8;

    // ---- stage K rows [w*64, w*64+64) and V^T tile w (once per block) ----
    {
        const size_t kbase = ((size_t)(b * 512 + w * 64)) * 1024 + h * 64;
        const size_t vbase = ((size_t)bh * 64) * 512;
#pragma unroll
        for (int c = 0; c < 8; ++c) {
            GLL16(kb + kbase + (size_t)(c * 8 + sr) * 1024 + sc, Kall + w * 4096 + c * 512);
            GLL16(vT + vbase + (size_t)(c * 8 + sr) * 512 + w * 64 + sc, Vall + w * 4096 + c * 512);
        }
    }
    __syncthreads();

    const float po = sigm(pl[3]);
    const float c0o = __logf(po + EPS_) - __logf(1.0f - po + EPS_);
    const float inv1mpo = 1.0f / (1.0f - po);

    for (int qt = 0; qt < 4; ++qt) {
        const int xg = qt * 128 + w * 16 + li;

        // Q fragments straight from global (B-operand of swapped QK^T)
        const unsigned short* qp = qb + ((size_t)(b * 512 + xg)) * 1024 + h * 64 + g * 8;
        bf16x8 qf0 = *(const bf16x8*)qp;
        bf16x8 qf1 = *(const bf16x8*)(qp + 32);

        f32x4 acc[32];
#pragma unroll
        for (int f = 0; f < 32; ++f) acc[f] = (f32x4){0.f, 0.f, 0.f, 0.f};

        // ---- QK^T: no barriers, K fully resident ----
#pragma unroll
        for (int f = 0; f < 32; ++f) {
            bf16x8 kf0 = ldsfrag64(Kall, f * 16 + li, g * 8);
            bf16x8 kf1 = ldsfrag64(Kall, f * 16 + li, g * 8 + 32);
            acc[f] = __builtin_amdgcn_mfma_f32_16x16x32_bf16(kf0, qf0, acc[f], 0, 0, 0);
            acc[f] = __builtin_amdgcn_mfma_f32_16x16x32_bf16(kf1, qf1, acc[f], 0, 0, 0);
        }

        // ---- masked softmax over y (x = xg fixed per lane) ----
        const bool vx = (xg <= len);
        float mx = -3.4e38f;
#pragma unroll
        for (int f = 0; f < 32; ++f)
#pragma unroll
            for (int r = 0; r < 4; ++r) {
                int y = f * 16 + g * 4 + r;
                float s = (vx && (y <= len)) ? acc[f][r] * 0.125f : -1e10f;
                acc[f][r] = s;
                mx = fmaxf(mx, s);
            }
        mx = fmaxf(mx, __shfl_xor(mx, 16));
        mx = fmaxf(mx, __shfl_xor(mx, 32));
        float sum = 0.f;
#pragma unroll
        for (int f = 0; f < 32; ++f)
#pragma unroll
            for (int r = 0; r < 4; ++r) {
                float e = __expf(acc[f][r] - mx);
                acc[f][r] = e;
                sum += e;
            }
        sum += __shfl_xor(sum, 16);
        sum += __shfl_xor(sum, 32);
        const float inv = 1.0f / sum;

        // normalize + write alpha (regular f32x4 stores — L2/L3 absorb)
        float* arow = alpha + ((size_t)bh * 512 + xg) * 512;
#pragma unroll
        for (int f = 0; f < 32; ++f) {
            f32x4 av = acc[f];
            av[0] *= inv; av[1] *= inv; av[2] *= inv; av[3] *= inv;
            acc[f] = av;
            *(f32x4*)(arow + f * 16 + g * 4) = av;
        }

        // ---- PV: register-P fragments x LDS V^T, no barriers ----
        f32x4 acco[4];
#pragma unroll
        for (int cf = 0; cf < 4; ++cf) acco[cf] = (f32x4){0.f, 0.f, 0.f, 0.f};

#pragma unroll
        for (int yt = 0; yt < 8; ++yt) {
            const unsigned short* Vc = Vall + yt * 4096;
#pragma unroll
            for (int w2 = 0; w2 < 2; ++w2) {
                int f0 = yt * 4 + w2 * 2;
                bf16x8 pf;
#pragma unroll
                for (int r = 0; r < 4; ++r) {
                    pf[r]     = (short)f2bf(acc[f0][r]);
                    pf[4 + r] = (short)f2bf(acc[f0 + 1][r]);
                }
#pragma unroll
                for (int cf = 0; cf < 4; ++cf) {
                    int d = cf * 16 + li;
                    int s0 = w2 * 8 + g;
                    int s1 = s0 + 4;
                    int p0 = (((s0 >> 1) ^ (d & 7)) << 3) + ((s0 & 1) << 2);
                    int p1 = (((s1 >> 1) ^ (d & 7)) << 3) + ((s1 & 1) << 2);
                    bf16x4 lo = *(const bf16x4*)(Vc + d * 64 + p0);
                    bf16x4 hi = *(const bf16x4*)(Vc + d * 64 + p1);
                    bf16x8 vf;
#pragma unroll
                    for (int e = 0; e < 4; ++e) { vf[e] = lo[e]; vf[4 + e] = hi[e]; }
                    acco[cf] = __builtin_amdgcn_mfma_f32_16x16x32_bf16(pf, vf, acco[cf], 0, 0, 0);
                }
            }
        }

        // ---- O scatter to LDS (bf16), then fused dropout + coalesced Ao write ----
#pragma unroll
        for (int cf = 0; cf < 4; ++cf)
#pragma unroll
            for (int r = 0; r < 4; ++r)
                Olb[(w * 16 + g * 4 + r) * 72 + cf * 16 + li] = f2bf(acco[cf][r]);
        __syncthreads();

#pragma unroll
        for (int i = 0; i < 2; ++i) {
            int idx = tid + i * 512;
            int xr = idx >> 3, d0 = (idx & 7) * 8;
            int xglob = qt * 128 + xr;
            const float* nop = no + ((size_t)(b * 512 + xglob)) * 1024 + h * 64 + d0;
            float4 n0 = *(const float4*)nop;
            float4 n1 = *(const float4*)(nop + 4);
            float nn[8] = {n0.x, n0.y, n0.z, n0.w, n1.x, n1.y, n1.z, n1.w};
            us8 ov = *(const us8*)&Olb[xr * 72 + d0];
            ushort o[8];
#pragma unroll
            for (int e = 0; e < 8; ++e) {
                float val = __uint_as_float(((unsigned)ov[e]) << 16);
                float lt = (c0o + __logf(nn[e] + EPS_) - __logf(1.0f - nn[e] + EPS_)) * INV_TEMP_;
                o[e] = f2bf(val * (1.0f - sigm(lt)) * inv1mpo);
            }
            *(us8*)(Ao + ((size_t)(b * 512 + xglob)) * 1024 + h * 64 + d0) = *(us8*)o;
        }
        __syncthreads();   // Olb reusable next pass
    }
}

// ---------------------------------------------------------------------------
extern "C" void kernel_launch(void* const* d_in, const int* in_sizes, int n_in,
                              void* d_out, int out_size, void* d_ws, size_t ws_size,
                              hipStream_t stream)
{
    const float* x       = (const float*)d_in[0];
    const int*   lengths = (const int*)d_in[1];
    const float* Wq      = (const float*)d_in[2];
    const float* Wk      = (const float*)d_in[3];
    const float* Wv      = (const float*)d_in[4];
    const float* Wo      = (const float*)d_in[5];
    const float* pl      = (const float*)d_in[6];
    const float* nq      = (const float*)d_in[7];
    const float* nk      = (const float*)d_in[8];
    const float* nv      = (const float*)d_in[9];
    const float* no      = (const float*)d_in[10];

    float* outp   = (float*)d_out;
    float* alphaF = outp + (size_t)M_ * D_;             // [B,H,S,S]

    const size_t chunk = (size_t)M_ * HD_;              // 16.78M elements
    // ws: qb,kb,vT,Ao bf16 (4 x 33.55MB) + WTo (2MB) = 136.2MB
    unsigned short* qb  = (unsigned short*)d_ws;
    unsigned short* kb  = qb + chunk;
    unsigned short* vT  = kb + chunk;
    unsigned short* Ao  = vT + chunk;
    unsigned short* WTo = Ao + chunk;

    // bf16 staging in the alpha region (dead until fused_attn writes it).
    unsigned short* WTq = (unsigned short*)(alphaF);
    unsigned short* Aq  = (unsigned short*)(alphaF + 1572864);
    unsigned short* WTk = WTq + (size_t)1024 * 1024;
    unsigned short* WTv = WTk + (size_t)1024 * 1024;

    dim3 blk(256);
    wcast_t4_kernel<<<dim3(16, 16, 4), blk, 0, stream>>>(Wq, Wk, Wv, Wo, WTq, WTk, WTv, WTo);

    cd_cast3_kernel<<<8192, blk, 0, stream>>>(x, nq, nk, nv, pl, Aq, Aq + chunk, Aq + 2 * chunk);

    gemm_qkv_kernel<<<dim3(1024, 3), blk, 0, stream>>>(Aq, WTq, qb, vT);

    fused_attn2_kernel<<<512, 512, 0, stream>>>(qb, kb, vT, no, pl, lengths, alphaF, Ao);

    gemm_o_kernel<<<1024, blk, 0, stream>>>(Ao, WTo, outp);
}

// Round 15
// 458.144 us; speedup vs baseline: 1.0404x; 1.0404x over previous
//
#include <hip/hip_runtime.h>

// Problem constants
constexpr int B_ = 32, S_ = 512, D_ = 1024, H_ = 16, DH_ = 64, HD_ = 1024;
constexpr int M_ = B_ * S_;                 // 16384
constexpr float EPS_ = 1e-7f;
constexpr float INV_TEMP_ = 10.0f;          // 1/0.1

typedef __attribute__((ext_vector_type(8))) short bf16x8;
typedef __attribute__((ext_vector_type(4))) short bf16x4;
typedef __attribute__((ext_vector_type(4))) float f32x4;
typedef __attribute__((ext_vector_type(8))) unsigned short us8;

__device__ __forceinline__ float sigm(float x) { return 1.0f / (1.0f + __expf(-x)); }

__device__ __forceinline__ unsigned short f2bf(float f) {
    unsigned u = __float_as_uint(f);
    unsigned r = (u + 0x7FFFu + ((u >> 16) & 1u)) >> 16;   // RNE
    return (unsigned short)r;
}

#define GLL16(gp, lp) __builtin_amdgcn_global_load_lds( \
    (const __attribute__((address_space(1))) unsigned int*)(gp), \
    (__attribute__((address_space(3))) unsigned int*)(lp), 16, 0, 0)

// LDS fragment read with XOR swizzle: element = row*64 + ((k>>3 ^ (row&7))*8)
__device__ __forceinline__ bf16x8 ldsfrag64(const unsigned short* base, int row, int k) {
    int slot = ((k >> 3) ^ (row & 7)) << 3;
    return *(const bf16x8*)(base + row * 64 + slot);
}

// ---------------------------------------------------------------------------
// Concrete-dropout + bf16 cast for q/k/v inputs (reads x once).
// ---------------------------------------------------------------------------
__global__ __launch_bounds__(256)
void cd_cast3_kernel(const float* __restrict__ x,
                     const float* __restrict__ nq, const float* __restrict__ nk,
                     const float* __restrict__ nv, const float* __restrict__ pl,
                     unsigned short* __restrict__ aq, unsigned short* __restrict__ ak,
                     unsigned short* __restrict__ av)
{
    size_t i0 = ((size_t)blockIdx.x * 256 + threadIdx.x) * 8;

    float c0[3], inv1mp[3];
#pragma unroll
    for (int j = 0; j < 3; ++j) {
        float p = sigm(pl[j]);
        c0[j] = __logf(p + EPS_) - __logf(1.0f - p + EPS_);
        inv1mp[j] = 1.0f / (1.0f - p);
    }

    float4 x0 = *(const float4*)(x + i0);
    float4 x1 = *(const float4*)(x + i0 + 4);
    float xv[8] = {x0.x, x0.y, x0.z, x0.w, x1.x, x1.y, x1.z, x1.w};

    const float* ns[3] = {nq, nk, nv};
    unsigned short* os[3] = {aq, ak, av};
#pragma unroll
    for (int j = 0; j < 3; ++j) {
        float4 u0 = *(const float4*)(ns[j] + i0);
        float4 u1 = *(const float4*)(ns[j] + i0 + 4);
        float uv[8] = {u0.x, u0.y, u0.z, u0.w, u1.x, u1.y, u1.z, u1.w};
        ushort out[8];
#pragma unroll
        for (int t = 0; t < 8; ++t) {
            float lt = (c0[j] + __logf(uv[t] + EPS_) - __logf(1.0f - uv[t] + EPS_)) * INV_TEMP_;
            float dpr = sigm(lt);
            out[t] = f2bf(xv[t] * (1.0f - dpr) * inv1mp[j]);
        }
        *(us8*)(os[j] + i0) = *(us8*)out;
    }
}

// ---------------------------------------------------------------------------
// Weight cast + transpose (all 4 weights in one launch): W[k][n] -> WT[n][k] bf16
// ---------------------------------------------------------------------------
__global__ __launch_bounds__(256)
void wcast_t4_kernel(const float* __restrict__ W0, const float* __restrict__ W1,
                     const float* __restrict__ W2, const float* __restrict__ W3,
                     unsigned short* __restrict__ T0, unsigned short* __restrict__ T1,
                     unsigned short* __restrict__ T2, unsigned short* __restrict__ T3)
{
    __shared__ unsigned short t[64][72];
    int z = blockIdx.z;
    const float* W = (z & 2) ? ((z & 1) ? W3 : W2) : ((z & 1) ? W1 : W0);
    unsigned short* WT = (z & 2) ? ((z & 1) ? T3 : T2) : ((z & 1) ? T1 : T0);
    int kb = blockIdx.y * 64;
    int nb = blockIdx.x * 64;
    int tid = threadIdx.x;
#pragma unroll
    for (int i = 0; i < 4; ++i) {
        int idx = tid + i * 256;
        int r = idx >> 4, c4 = idx & 15;
        float4 v = *(const float4*)(W + (size_t)(kb + r) * 1024 + nb + c4 * 4);
        t[c4 * 4 + 0][r] = f2bf(v.x);
        t[c4 * 4 + 1][r] = f2bf(v.y);
        t[c4 * 4 + 2][r] = f2bf(v.z);
        t[c4 * 4 + 3][r] = f2bf(v.w);
    }
    __syncthreads();
#pragma unroll
    for (int i = 0; i < 4; ++i) {
        int idx = tid + i * 256;
        int r = idx >> 4, c4 = idx & 15;
        ushort4 o;
        o.x = t[r][c4 * 4 + 0];
        o.y = t[r][c4 * 4 + 1];
        o.z = t[r][c4 * 4 + 2];
        o.w = t[r][c4 * 4 + 3];
        *(ushort4*)(WT + (size_t)(nb + r) * 1024 + kb + c4 * 4) = o;
    }
}

// ---------------------------------------------------------------------------
// QKV bf16 MFMA GEMM, BK=64: swizzled-source GLL16 staging, conflict-free
// ldsfrag64 reads, vectorized LDS-bounce epilogue.
// zo=blockIdx.y: 0->qb, 1->kb, 2->vT (transposed write, fuses vtrans).
// ---------------------------------------------------------------------------
__global__ __launch_bounds__(256, 3)
void gemm_qkv_kernel(const unsigned short* __restrict__ A,
                     const unsigned short* __restrict__ BT,
                     unsigned short* __restrict__ qkb,
                     unsigned short* __restrict__ vT)
{
    const int zo = blockIdx.y;
    A  += (size_t)zo * M_ * HD_;
    BT += (size_t)zo * (1024 * 1024);

    // staging 2 x 128x64 bf16 (32KB); epilogue bounce (17.4KB) reuses it
    __shared__ unsigned short LDSU[16384];
    unsigned short* As = LDSU;            // [128][64] swizzled
    unsigned short* Bs = LDSU + 8192;     // [128][64] swizzled

    int flat = blockIdx.x;
    int swz = (flat & 7) * 128 + (flat >> 3);
    int ntile = swz & 7, mtile = swz >> 3;
    int m0 = mtile * 128, n0 = ntile * 128;

    int tid = threadIdx.x;
    int w = tid >> 6, lane = tid & 63;
    int wm = w >> 1, wn = w & 1;

    f32x4 acc[4][4];
#pragma unroll
    for (int m = 0; m < 4; ++m)
#pragma unroll
        for (int n = 0; n < 4; ++n) acc[m][n] = (f32x4){0.f, 0.f, 0.f, 0.f};

    const int sr = lane >> 3;                 // row within 8-row chunk
    const int sc = ((lane & 7) ^ sr) * 8;     // pre-swizzled source col (elems)

    const unsigned short* Ag = A + (size_t)(m0 + w * 32 + sr) * 1024 + sc;
    const unsigned short* Bg = BT + (size_t)(n0 + w * 32 + sr) * 1024 + sc;
    unsigned short* AsW = As + (w * 32) * 64;
    unsigned short* BsW = Bs + (w * 32) * 64;

    const int arow = wm * 64 + (lane & 15);
    const int brow = wn * 64 + (lane & 15);
    const int g8 = (lane >> 4) * 8;

    for (int k0 = 0; k0 < 1024; k0 += 64) {
        __syncthreads();
#pragma unroll
        for (int c = 0; c < 4; ++c) {
            GLL16(Ag + k0 + (size_t)(c * 8) * 1024, AsW + c * 512);
            GLL16(Bg + k0 + (size_t)(c * 8) * 1024, BsW + c * 512);
        }
        __syncthreads();

#pragma unroll
        for (int kk = 0; kk < 2; ++kk) {
            bf16x8 afr[4], bfr[4];
#pragma unroll
            for (int m = 0; m < 4; ++m)
                afr[m] = ldsfrag64(As, arow + m * 16, g8 + kk * 32);
#pragma unroll
            for (int n = 0; n < 4; ++n)
                bfr[n] = ldsfrag64(Bs, brow + n * 16, g8 + kk * 32);
#pragma unroll
            for (int m = 0; m < 4; ++m)
#pragma unroll
                for (int n = 0; n < 4; ++n)
                    acc[m][n] = __builtin_amdgcn_mfma_f32_16x16x32_bf16(afr[m], bfr[n], acc[m][n], 0, 0, 0);
        }
    }

    const int cr = (lane >> 4) * 4, cc = lane & 15;
    __syncthreads();   // staging LDS free for bounce

    if (zo < 2) {
        // flat bf16 output, chunked by n-frag through LDS [128][68] (32 cols used)
        unsigned short* Cb = qkb + (size_t)zo * M_ * HD_;
        for (int n = 0; n < 4; ++n) {
#pragma unroll
            for (int m = 0; m < 4; ++m)
#pragma unroll
                for (int j = 0; j < 4; ++j)
                    LDSU[(wm * 64 + m * 16 + cr + j) * 68 + wn * 16 + cc] = f2bf(acc[m][n][j]);
            __syncthreads();
#pragma unroll
            for (int t = 0; t < 2; ++t) {
                int fl = tid + t * 256;            // 0..511
                int row = fl >> 2, p = fl & 3;     // row 0..127, p 0..3
                us8 vv = *(const us8*)&LDSU[row * 68 + p * 8];
                int colg = n0 + (p >> 1) * 64 + n * 16 + (p & 1) * 8;
                *(us8*)(Cb + (size_t)(m0 + row) * 1024 + colg) = vv;
            }
            __syncthreads();
        }
    } else {
        // V slice: write vT[b,h,d,y] directly via transposed bounce LDS [32][132]
        int b = m0 >> 9, y0 = m0 & 511, h0 = n0 >> 6;
        for (int n = 0; n < 4; ++n) {
#pragma unroll
            for (int m = 0; m < 4; ++m)
#pragma unroll
                for (int j = 0; j < 4; ++j)
                    LDSU[(wn * 16 + cc) * 132 + wm * 64 + m * 16 + cr + j] = f2bf(acc[m][n][j]);
            __syncthreads();
#pragma unroll
            for (int t = 0; t < 2; ++t) {
                int fl = tid + t * 256;            // 0..511
                int cl = fl >> 4, yp = fl & 15;    // cl 0..31, yp 0..15
                us8 vv = *(const us8*)&LDSU[cl * 132 + yp * 8];
                int h = h0 + (cl >> 4), d = n * 16 + (cl & 15);
                *(us8*)(vT + ((size_t)((b * 16 + h) * 64 + d)) * 512 + y0 + yp * 8) = vv;
            }
            __syncthreads();
        }
    }
}

// ---------------------------------------------------------------------------
// O-projection GEMM, BK=64 (same staging/read pattern), RELU, fp32 out.
// ---------------------------------------------------------------------------
__global__ __launch_bounds__(256, 3)
void gemm_o_kernel(const unsigned short* __restrict__ A,
                   const unsigned short* __restrict__ BT,
                   float* __restrict__ C)
{
    __shared__ unsigned short As[128 * 64];
    __shared__ unsigned short Bs[128 * 64];

    int flat = blockIdx.x;
    int swz = (flat & 7) * 128 + (flat >> 3);
    int ntile = swz & 7, mtile = swz >> 3;
    int m0 = mtile * 128, n0 = ntile * 128;

    int tid = threadIdx.x;
    int w = tid >> 6, lane = tid & 63;
    int wm = w >> 1, wn = w & 1;

    f32x4 acc[4][4];
#pragma unroll
    for (int m = 0; m < 4; ++m)
#pragma unroll
        for (int n = 0; n < 4; ++n) acc[m][n] = (f32x4){0.f, 0.f, 0.f, 0.f};

    const int sr = lane >> 3;
    const int sc = ((lane & 7) ^ sr) * 8;

    const unsigned short* Ag = A + (size_t)(m0 + w * 32 + sr) * 1024 + sc;
    const unsigned short* Bg = BT + (size_t)(n0 + w * 32 + sr) * 1024 + sc;
    unsigned short* AsW = As + (w * 32) * 64;
    unsigned short* BsW = Bs + (w * 32) * 64;

    const int arow = wm * 64 + (lane & 15);
    const int brow = wn * 64 + (lane & 15);
    const int g8 = (lane >> 4) * 8;

    for (int k0 = 0; k0 < 1024; k0 += 64) {
        __syncthreads();
#pragma unroll
        for (int c = 0; c < 4; ++c) {
            GLL16(Ag + k0 + (size_t)(c * 8) * 1024, AsW + c * 512);
            GLL16(Bg + k0 + (size_t)(c * 8) * 1024, BsW + c * 512);
        }
        __syncthreads();

#pragma unroll
        for (int kk = 0; kk < 2; ++kk) {
            bf16x8 afr[4], bfr[4];
#pragma unroll
            for (int m = 0; m < 4; ++m)
                afr[m] = ldsfrag64(As, arow + m * 16, g8 + kk * 32);
#pragma unroll
            for (int n = 0; n < 4; ++n)
                bfr[n] = ldsfrag64(Bs, brow + n * 16, g8 + kk * 32);
#pragma unroll
            for (int m = 0; m < 4; ++m)
#pragma unroll
                for (int n = 0; n < 4; ++n)
                    acc[m][n] = __builtin_amdgcn_mfma_f32_16x16x32_bf16(afr[m], bfr[n], acc[m][n], 0, 0, 0);
        }
    }

    int cr = (lane >> 4) * 4, cc = lane & 15;
#pragma unroll
    for (int m = 0; m < 4; ++m)
#pragma unroll
        for (int n = 0; n < 4; ++n)
#pragma unroll
            for (int j = 0; j < 4; ++j) {
                int row = m0 + wm * 64 + m * 16 + cr + j;
                int col = n0 + wn * 64 + n * 16 + cc;
                C[(size_t)row * 1024 + col] = fmaxf(acc[m][n][j], 0.f);
            }
}

// ---------------------------------------------------------------------------
// Fused attention v2 (R13 champion + NT alpha stores restored + T14-style
// o-noise prefetch: the epilogue's `no` loads issue at pass TOP, hiding their
// HBM/L2 latency under QK^T+softmax instead of serially blocking the Ao write).
// ---------------------------------------------------------------------------
__global__ __launch_bounds__(512, 2)
void fused_attn2_kernel(const unsigned short* __restrict__ qb,
                        const unsigned short* __restrict__ kb,
                        const unsigned short* __restrict__ vT,
                        const float* __restrict__ no,
                        const float* __restrict__ pl,
                        const int* __restrict__ lengths,
                        float* __restrict__ alpha,
                        unsigned short* __restrict__ Ao)
{
    const int bh = blockIdx.x;
    const int b = bh >> 4, h = bh & 15;
    const int tid = threadIdx.x;
    const int w = tid >> 6, lane = tid & 63;
    const int g = lane >> 4, li = lane & 15;
    const int len = lengths[b];

    __shared__ unsigned short Kall[512 * 64];      // [y][64k] swizzled (8 tiles)
    __shared__ unsigned short Vall[8 * 64 * 64];   // tile yt: [d][64y] swizzled
    __shared__ unsigned short Olb[128 * 72];       // O pass tile, bf16

    const int sr = lane >> 3;
    const int sc = ((lane & 7) ^ sr) * 8;

    // ---- stage K rows [w*64, w*64+64) and V^T tile w (once per block) ----
    {
        const size_t kbase = ((size_t)(b * 512 + w * 64)) * 1024 + h * 64;
        const size_t vbase = ((size_t)bh * 64) * 512;
#pragma unroll
        for (int c = 0; c < 8; ++c) {
            GLL16(kb + kbase + (size_t)(c * 8 + sr) * 1024 + sc, Kall + w * 4096 + c * 512);
            GLL16(vT + vbase + (size_t)(c * 8 + sr) * 512 + w * 64 + sc, Vall + w * 4096 + c * 512);
        }
    }
    __syncthreads();

    const float po = sigm(pl[3]);
    const float c0o = __logf(po + EPS_) - __logf(1.0f - po + EPS_);
    const float inv1mpo = 1.0f / (1.0f - po);

    for (int qt = 0; qt < 4; ++qt) {
        const int xg = qt * 128 + w * 16 + li;

        // ---- prefetch this pass's o-noise (use-late in the epilogue) ----
        float4 pn0[2], pn1[2];
#pragma unroll
        for (int i = 0; i < 2; ++i) {
            int idx = tid + i * 512;
            int xr = idx >> 3, d0 = (idx & 7) * 8;
            const float* nop = no + ((size_t)(b * 512 + qt * 128 + xr)) * 1024 + h * 64 + d0;
            pn0[i] = *(const float4*)nop;
            pn1[i] = *(const float4*)(nop + 4);
        }

        // Q fragments straight from global (B-operand of swapped QK^T)
        const unsigned short* qp = qb + ((size_t)(b * 512 + xg)) * 1024 + h * 64 + g * 8;
        bf16x8 qf0 = *(const bf16x8*)qp;
        bf16x8 qf1 = *(const bf16x8*)(qp + 32);

        f32x4 acc[32];
#pragma unroll
        for (int f = 0; f < 32; ++f) acc[f] = (f32x4){0.f, 0.f, 0.f, 0.f};

        // ---- QK^T: no barriers, K fully resident ----
#pragma unroll
        for (int f = 0; f < 32; ++f) {
            bf16x8 kf0 = ldsfrag64(Kall, f * 16 + li, g * 8);
            bf16x8 kf1 = ldsfrag64(Kall, f * 16 + li, g * 8 + 32);
            acc[f] = __builtin_amdgcn_mfma_f32_16x16x32_bf16(kf0, qf0, acc[f], 0, 0, 0);
            acc[f] = __builtin_amdgcn_mfma_f32_16x16x32_bf16(kf1, qf1, acc[f], 0, 0, 0);
        }

        // ---- masked softmax over y (x = xg fixed per lane) ----
        const bool vx = (xg <= len);
        float mx = -3.4e38f;
#pragma unroll
        for (int f = 0; f < 32; ++f)
#pragma unroll
            for (int r = 0; r < 4; ++r) {
                int y = f * 16 + g * 4 + r;
                float s = (vx && (y <= len)) ? acc[f][r] * 0.125f : -1e10f;
                acc[f][r] = s;
                mx = fmaxf(mx, s);
            }
        mx = fmaxf(mx, __shfl_xor(mx, 16));
        mx = fmaxf(mx, __shfl_xor(mx, 32));
        float sum = 0.f;
#pragma unroll
        for (int f = 0; f < 32; ++f)
#pragma unroll
            for (int r = 0; r < 4; ++r) {
                float e = __expf(acc[f][r] - mx);
                acc[f][r] = e;
                sum += e;
            }
        sum += __shfl_xor(sum, 16);
        sum += __shfl_xor(sum, 32);
        const float inv = 1.0f / sum;

        // normalize + write alpha (non-temporal f32x4 vector stores)
        float* arow = alpha + ((size_t)bh * 512 + xg) * 512;
#pragma unroll
        for (int f = 0; f < 32; ++f) {
            f32x4 av = acc[f];
            av[0] *= inv; av[1] *= inv; av[2] *= inv; av[3] *= inv;
            acc[f] = av;
            __builtin_nontemporal_store(av, (f32x4*)(arow + f * 16 + g * 4));
        }

        // ---- PV: register-P fragments x LDS V^T, no barriers ----
        f32x4 acco[4];
#pragma unroll
        for (int cf = 0; cf < 4; ++cf) acco[cf] = (f32x4){0.f, 0.f, 0.f, 0.f};

#pragma unroll
        for (int yt = 0; yt < 8; ++yt) {
            const unsigned short* Vc = Vall + yt * 4096;
#pragma unroll
            for (int w2 = 0; w2 < 2; ++w2) {
                int f0 = yt * 4 + w2 * 2;
                bf16x8 pf;
#pragma unroll
                for (int r = 0; r < 4; ++r) {
                    pf[r]     = (short)f2bf(acc[f0][r]);
                    pf[4 + r] = (short)f2bf(acc[f0 + 1][r]);
                }
#pragma unroll
                for (int cf = 0; cf < 4; ++cf) {
                    int d = cf * 16 + li;
                    int s0 = w2 * 8 + g;
                    int s1 = s0 + 4;
                    int p0 = (((s0 >> 1) ^ (d & 7)) << 3) + ((s0 & 1) << 2);
                    int p1 = (((s1 >> 1) ^ (d & 7)) << 3) + ((s1 & 1) << 2);
                    bf16x4 lo = *(const bf16x4*)(Vc + d * 64 + p0);
                    bf16x4 hi = *(const bf16x4*)(Vc + d * 64 + p1);
                    bf16x8 vf;
#pragma unroll
                    for (int e = 0; e < 4; ++e) { vf[e] = lo[e]; vf[4 + e] = hi[e]; }
                    acco[cf] = __builtin_amdgcn_mfma_f32_16x16x32_bf16(pf, vf, acco[cf], 0, 0, 0);
                }
            }
        }

        // ---- O scatter to LDS (bf16), then fused dropout + coalesced Ao write ----
#pragma unroll
        for (int cf = 0; cf < 4; ++cf)
#pragma unroll
            for (int r = 0; r < 4; ++r)
                Olb[(w * 16 + g * 4 + r) * 72 + cf * 16 + li] = f2bf(acco[cf][r]);
        __syncthreads();

#pragma unroll
        for (int i = 0; i < 2; ++i) {
            int idx = tid + i * 512;
            int xr = idx >> 3, d0 = (idx & 7) * 8;
            int xglob = qt * 128 + xr;
            float nn[8] = {pn0[i].x, pn0[i].y, pn0[i].z, pn0[i].w,
                           pn1[i].x, pn1[i].y, pn1[i].z, pn1[i].w};
            us8 ov = *(const us8*)&Olb[xr * 72 + d0];
            ushort o[8];
#pragma unroll
            for (int e = 0; e < 8; ++e) {
                float val = __uint_as_float(((unsigned)ov[e]) << 16);
                float lt = (c0o + __logf(nn[e] + EPS_) - __logf(1.0f - nn[e] + EPS_)) * INV_TEMP_;
                o[e] = f2bf(val * (1.0f - sigm(lt)) * inv1mpo);
            }
            *(us8*)(Ao + ((size_t)(b * 512 + xglob)) * 1024 + h * 64 + d0) = *(us8*)o;
        }
        __syncthreads();   // Olb reusable next pass
    }
}

// ---------------------------------------------------------------------------
extern "C" void kernel_launch(void* const* d_in, const int* in_sizes, int n_in,
                              void* d_out, int out_size, void* d_ws, size_t ws_size,
                              hipStream_t stream)
{
    const float* x       = (const float*)d_in[0];
    const int*   lengths = (const int*)d_in[1];
    const float* Wq      = (const float*)d_in[2];
    const float* Wk      = (const float*)d_in[3];
    const float* Wv      = (const float*)d_in[4];
    const float* Wo      = (const float*)d_in[5];
    const float* pl      = (const float*)d_in[6];
    const float* nq      = (const float*)d_in[7];
    const float* nk      = (const float*)d_in[8];
    const float* nv      = (const float*)d_in[9];
    const float* no      = (const float*)d_in[10];

    float* outp   = (float*)d_out;
    float* alphaF = outp + (size_t)M_ * D_;             // [B,H,S,S]

    const size_t chunk = (size_t)M_ * HD_;              // 16.78M elements
    // ws: qb,kb,vT,Ao bf16 (4 x 33.55MB) + WTo (2MB) = 136.2MB
    unsigned short* qb  = (unsigned short*)d_ws;
    unsigned short* kb  = qb + chunk;
    unsigned short* vT  = kb + chunk;
    unsigned short* Ao  = vT + chunk;
    unsigned short* WTo = Ao + chunk;

    // bf16 staging in the alpha region (dead until fused_attn writes it).
    unsigned short* WTq = (unsigned short*)(alphaF);
    unsigned short* Aq  = (unsigned short*)(alphaF + 1572864);
    unsigned short* WTk = WTq + (size_t)1024 * 1024;
    unsigned short* WTv = WTk + (size_t)1024 * 1024;

    dim3 blk(256);
    wcast_t4_kernel<<<dim3(16, 16, 4), blk, 0, stream>>>(Wq, Wk, Wv, Wo, WTq, WTk, WTv, WTo);

    cd_cast3_kernel<<<8192, blk, 0, stream>>>(x, nq, nk, nv, pl, Aq, Aq + chunk, Aq + 2 * chunk);

    gemm_qkv_kernel<<<dim3(1024, 3), blk, 0, stream>>>(Aq, WTq, qb, vT);

    fused_attn2_kernel<<<512, 512, 0, stream>>>(qb, kb, vT, no, pl, lengths, alphaF, Ao);

    gemm_o_kernel<<<1024, blk, 0, stream>>>(Ao, WTo, outp);
}